// Round 12
// baseline (131.675 us; speedup 1.0000x reference)
//
#include <hip/hip_runtime.h>
#include <hip/hip_fp16.h>

// MyEncoder: B=8, S=4096, E=128, D=24, fp32 in/out.
// out = softmax((xWq+bq)(xWk+bk)^T / sqrt(128)) (xWv+bv) Wo + bo
// bf16-MFMA pipeline (3 kernels): proj (QKV GEMM, builds its own weight
// frags in LDS; writes Kbf PRE-PERMUTED for attn) -> attn (flash partials,
// K-split, 16x16x32 transposed scores, in-register P, full-K PV,
// MFMA-computed l, TK=256) -> combine (sum fp16 partials + wO epilogue,
// builds wO frags in LDS). Softmax without max-subtraction (scores tiny,
// shift-invariant) => K-split partials purely additive. exp2 with log2(e)
// folded into Q scale.

#define B_ 8
#define S_ 4096
#define E_ 128
#define D_ 24
#define N_ (B_ * S_)               // 32768 rows
#define SCALE 0.08838834764831845f // 1/sqrt(128)
#define LOG2E 1.4426950408889634f

#define TK 256                     // keys per LDS tile in attn
#define KS_STRIDE 40               // K_s row stride (shorts): 2-way only (free)
#define VS_STRIDE 264              // V_s row stride (shorts): 256 + 8 pad, 2-way
#define HS_STRIDE 40               // H_s row stride in combine
#define XS_STRIDE 136              // x_s row stride (bf16) in proj
#define OS_STRIDE 84               // out_s row stride (fp32) in proj

typedef __attribute__((ext_vector_type(8))) short bfrag;   // 8 bf16 = 4 VGPR
typedef __attribute__((ext_vector_type(4))) float ffrag;   // 4 fp32 acc

__device__ inline unsigned short f2bf(float f) {           // RNE fp32->bf16
    unsigned int x = __builtin_bit_cast(unsigned int, f);
    return (unsigned short)((x + 0x7fffu + ((x >> 16) & 1u)) >> 16);
}
// round-half-up bf16 pair pack: 2 int-adds + v_perm (validated r5-r10 on HW)
__device__ inline unsigned int pack2h(float a, float b) {
    unsigned int ua = __builtin_bit_cast(unsigned int, a) + 0x8000u;
    unsigned int ub = __builtin_bit_cast(unsigned int, b) + 0x8000u;
    return __builtin_amdgcn_perm(ub, ua, 0x07060302);      // [a.hi16 | b.hi16]
}
// fp16 pair pack, RTZ, single v_cvt_pkrtz_f16_f32
__device__ inline unsigned int packh16(float a, float b) {
    return __builtin_bit_cast(unsigned int, __builtin_amdgcn_cvt_pkrtz(a, b));
}

// ---------------- Kernel 1: QKV projection (MFMA) ----------------
// 64 rows/block, 4 waves x 16 rows. Builds W fragments + biases in LDS from
// raw weights (replaces the old prep kernel; <1us chip-wide). Writes:
//   Qbf natural row-major (32-padded bf16)
//   Kbf PRE-PERMUTED within 32-key groups for attn's fragment layout
//   Vt transposed [b][d][s]
__global__ __launch_bounds__(256) void proj_kernel(
    const float* __restrict__ x,
    const float* __restrict__ wQ, const float* __restrict__ bQ,
    const float* __restrict__ wK, const float* __restrict__ bK,
    const float* __restrict__ wV, const float* __restrict__ bV,
    unsigned short* __restrict__ Qbf, unsigned short* __restrict__ Kbf,
    unsigned short* __restrict__ Vt)
{
    __shared__ float smem[64 * OS_STRIDE];          // 21504 B, dual-purpose
    __shared__ unsigned short WfL[4 * 5 * 512];     // 20480 B weight frags
    __shared__ float bqkvL[80];
    unsigned short* xs = (unsigned short*)smem;     // [64][XS_STRIDE]
    float* os = smem;                               // [64][OS_STRIDE]

    const int tid  = threadIdx.x;
    const int lane = tid & 63;
    const int w    = tid >> 6;
    const int col  = lane & 15;
    const int quad = lane >> 4;
    const int rb   = blockIdx.x * 64;
    const float qs = SCALE * LOG2E;

    // build weight fragments in LDS (formula identical to old prep kernel)
    for (int idx = tid; idx < 4 * 5 * 512; idx += 256) {
        const int j  = idx & 7;
        const int ln = (idx >> 3) & 63;
        const int nt = (idx >> 9) % 5;
        const int kt = idx / 2560;
        const int n = nt * 16 + (ln & 15);
        const int k = kt * 32 + ((ln >> 4) << 3) + j;
        float v = 0.0f;
        if (n < 24)      v = wQ[k * 24 + n] * qs;
        else if (n < 48) v = wK[k * 24 + (n - 24)];
        else if (n < 72) v = wV[k * 24 + (n - 48)];
        WfL[idx] = f2bf(v);
    }
    if (tid < 80) {
        float v = 0.0f;
        if (tid < 24)      v = bQ[tid] * qs;
        else if (tid < 48) v = bK[tid - 24];
        else if (tid < 72) v = bV[tid - 48];
        bqkvL[tid] = v;
    }

    // stage x -> bf16 LDS
    #pragma unroll
    for (int i = 0; i < 8; ++i) {
        const int idx = i * 256 + tid;
        const int row = idx >> 5, c4 = idx & 31;
        const float4 xv = *(const float4*)(x + (size_t)(rb + row) * 128 + c4 * 4);
        uint2 h;
        h.x = pack2h(xv.x, xv.y);
        h.y = pack2h(xv.z, xv.w);
        *(uint2*)(&xs[row * XS_STRIDE + c4 * 4]) = h;
    }

    __syncthreads();

    bfrag Wfr[20];
    #pragma unroll
    for (int f = 0; f < 20; ++f)
        Wfr[f] = *(const bfrag*)(&WfL[(f * 64 + lane) * 8]);

    ffrag acc[5];
    #pragma unroll
    for (int nt = 0; nt < 5; ++nt) acc[nt] = (ffrag){0.f, 0.f, 0.f, 0.f};

    #pragma unroll
    for (int kt = 0; kt < 4; ++kt) {
        const bfrag Af = *(const bfrag*)(&xs[(w * 16 + col) * XS_STRIDE + kt * 32 + quad * 8]);
        #pragma unroll
        for (int nt = 0; nt < 5; ++nt)
            acc[nt] = __builtin_amdgcn_mfma_f32_16x16x32_bf16(Af, Wfr[kt * 5 + nt], acc[nt], 0, 0, 0);
    }

    __syncthreads();  // reuse smem as fp32 out tile

    #pragma unroll
    for (int nt = 0; nt < 5; ++nt) {
        const float bb = bqkvL[nt * 16 + col];
        #pragma unroll
        for (int r = 0; r < 4; ++r)
            os[(w * 16 + quad * 4 + r) * OS_STRIDE + nt * 16 + col] = acc[nt][r] + bb;
    }
    __syncthreads();

    // Q (tid<128) natural / K (tid>=128) PRE-PERMUTED row-major bf16, 32-pad.
    // perm within 32-key group: bit pattern [k2,k4,k3,k1,k0] (matches attn's
    // fragment layout so attn staging is a straight copy).
    {
        const int half  = tid & 1;
        const int row   = (tid >> 1) & 63;
        const int isK   = tid >> 7;
        const int cbase = isK * 24;
        unsigned int pk[8];
        #pragma unroll
        for (int g = 0; g < 8; ++g) {
            const int c0 = half * 16 + g * 2;
            const float f0 = (c0     < 24) ? os[row * OS_STRIDE + cbase + c0]     : 0.0f;
            const float f1 = (c0 + 1 < 24) ? os[row * OS_STRIDE + cbase + c0 + 1] : 0.0f;
            pk[g] = pack2h(f0, f1);
        }
        const int gkey = rb + row;
        const int kl   = gkey & 31;
        const int gperm = (gkey & ~31) | ((kl & 4) << 2) | ((kl & 24) >> 1) | (kl & 3);
        unsigned short* dst = isK ? (Kbf + (size_t)gperm * 32 + half * 16)
                                  : (Qbf + (size_t)gkey  * 32 + half * 16);
        *(uint4*)(dst)     = make_uint4(pk[0], pk[1], pk[2], pk[3]);
        *(uint4*)(dst + 8) = make_uint4(pk[4], pk[5], pk[6], pk[7]);
    }

    // Vt: transposed [b][d][s], 16B stores
    if (tid < 192) {
        const int d  = tid % 24;
        const int ch = tid / 24;
        unsigned int p[4];
        #pragma unroll
        for (int g = 0; g < 4; ++g) {
            const float f0 = os[(ch * 8 + g * 2 + 0) * OS_STRIDE + 48 + d];
            const float f1 = os[(ch * 8 + g * 2 + 1) * OS_STRIDE + 48 + d];
            p[g] = pack2h(f0, f1);
        }
        const int b = rb >> 12, s0 = rb & 4095;
        uint4* dst = (uint4*)(Vt + (((size_t)(b * 24 + d)) << 12) + s0 + ch * 8);
        *dst = make_uint4(p[0], p[1], p[2], p[3]);
    }
}

// ---------------- Kernel 2: flash attention partials ----------------
// Grid (N/128, nsp). 512 threads = 8 waves x 16 q = 128 q/block. TK=256
// halves barrier count vs r8. Kbf arrives pre-permuted -> straight copy.
// Per 32-key group: 2 QK mfma (key-halves from the permuted layout), exp2,
// pack into ONE full K=32 P B-frag, 2 PV mfma. V row d=24 staged as 1.0 =>
// PV computes l in Ot1's d=24 element.
__global__ __launch_bounds__(512, 8) void attn_kernel(
    const unsigned short* __restrict__ Qbf, const unsigned short* __restrict__ Kbf,
    const unsigned short* __restrict__ Vt,
    __half* __restrict__ Opart, float* __restrict__ lpart)
{
    __shared__ unsigned short Ks[TK * KS_STRIDE];     // 20480 B
    __shared__ unsigned short Vs[32 * VS_STRIDE];     // 16896 B (rows 25-31 unused)

    const int tid    = threadIdx.x;
    const int lane   = tid & 63;
    const int w      = tid >> 6;                      // 0..7
    const int col    = lane & 15;
    const int quad   = lane >> 4;
    const int blk    = blockIdx.x;                    // 0..N/128-1
    const int split  = blockIdx.y;
    const int nsp    = gridDim.y;
    const int kchunk = S_ / nsp;
    const int b      = blk >> 5;                      // 32 blocks per batch
    const int qbase  = blk * 128 + w * 16;

    // ones row d=24 (256 keys = 32 uint4); staging only touches rows 0..23
    if (tid < 32)
        *(uint4*)(&Vs[24 * VS_STRIDE + tid * 8]) =
            make_uint4(0x3F803F80u, 0x3F803F80u, 0x3F803F80u, 0x3F803F80u);

    const bfrag Qf = *(const bfrag*)(Qbf + (size_t)(qbase + col) * 32 + quad * 8);

    ffrag Ot0 = {0.f, 0.f, 0.f, 0.f};   // O^T d = quad*4+r      (0..15)
    ffrag Ot1 = {0.f, 0.f, 0.f, 0.f};   // O^T d = 16+quad*4+r   (d=24 is l)

    const unsigned short* Kbase = Kbf + ((size_t)(b * 4096) + split * kchunk) * 32;
    const unsigned short* Vbase = Vt + (size_t)(b * 24) * 4096 + split * kchunk;

    __syncthreads();   // ones row visible

    for (int kb = 0; kb < kchunk; kb += TK) {
        // K tile: straight copy (permutation baked into Kbf), 256 keys x 32 bf16
        #pragma unroll
        for (int i = 0; i < 2; ++i) {
            const int idx = i * 512 + tid;            // 0..1023
            const int key = idx >> 2, ch = idx & 3;
            const uint4 t4 = *(const uint4*)(Kbase + (size_t)(kb + key) * 32 + ch * 8);
            *(uint4*)(&Ks[key * KS_STRIDE + ch * 8]) = t4;
        }
        // V tile: 24 d-rows x 256 keys, natural order (768 uint4)
        #pragma unroll
        for (int i = 0; i < 2; ++i) {
            const int u = i * 512 + tid;
            if (u < 768) {
                const int d = u >> 5, ch = u & 31;
                const uint4 t4 = *(const uint4*)(Vbase + (size_t)d * 4096 + kb + ch * 8);
                *(uint4*)(&Vs[d * VS_STRIDE + ch * 8]) = t4;
            }
        }
        __syncthreads();

        #pragma unroll
        for (int c2 = 0; c2 < TK / 32; ++c2) {
            const bfrag Kfe = *(const bfrag*)(&Ks[(c2 * 32 + col) * KS_STRIDE + quad * 8]);
            const bfrag Kfo = *(const bfrag*)(&Ks[(c2 * 32 + 16 + col) * KS_STRIDE + quad * 8]);
            ffrag Se = {0.f, 0.f, 0.f, 0.f};
            ffrag So = {0.f, 0.f, 0.f, 0.f};
            Se = __builtin_amdgcn_mfma_f32_16x16x32_bf16(Kfe, Qf, Se, 0, 0, 0);
            So = __builtin_amdgcn_mfma_f32_16x16x32_bf16(Kfo, Qf, So, 0, 0, 0);
            union { bfrag f; unsigned int u[4]; } P;
            P.u[0] = pack2h(__builtin_amdgcn_exp2f(Se[0]), __builtin_amdgcn_exp2f(Se[1]));
            P.u[1] = pack2h(__builtin_amdgcn_exp2f(Se[2]), __builtin_amdgcn_exp2f(Se[3]));
            P.u[2] = pack2h(__builtin_amdgcn_exp2f(So[0]), __builtin_amdgcn_exp2f(So[1]));
            P.u[3] = pack2h(__builtin_amdgcn_exp2f(So[2]), __builtin_amdgcn_exp2f(So[3]));
            const bfrag Va0 = *(const bfrag*)(&Vs[col * VS_STRIDE + c2 * 32 + quad * 8]);
            const bfrag Va1 = *(const bfrag*)(&Vs[(16 + col) * VS_STRIDE + c2 * 32 + quad * 8]);
            Ot0 = __builtin_amdgcn_mfma_f32_16x16x32_bf16(Va0, P.f, Ot0, 0, 0, 0);
            Ot1 = __builtin_amdgcn_mfma_f32_16x16x32_bf16(Va1, P.f, Ot1, 0, 0, 0);
        }
        __syncthreads();
    }

    // store fp16 partials: O^T -> Opart[q][d]; l from Ot1 d=24 (quad 2, r=0)
    const size_t base = ((size_t)split * N_ + qbase + col) * 32;
    {
        uint2 s0;
        s0.x = packh16(Ot0[0], Ot0[1]);
        s0.y = packh16(Ot0[2], Ot0[3]);
        *(uint2*)(Opart + base + quad * 4) = s0;
    }
    if (quad < 2) {
        uint2 s1;
        s1.x = packh16(Ot1[0], Ot1[1]);
        s1.y = packh16(Ot1[2], Ot1[3]);
        *(uint2*)(Opart + base + 16 + quad * 4) = s1;   // d 16..23
    }
    if (quad == 2)
        lpart[(size_t)split * N_ + qbase + col] = Ot1[0]; // d=24 = sum(P) = l
}

// ---------------- Kernel 3: combine + output projection ----------------
// Builds wO fragments in LDS from raw wO (replaces prep's wOf).
__global__ __launch_bounds__(256) void combine_kernel(
    const __half* __restrict__ Opart, const float* __restrict__ lpart,
    const float* __restrict__ wO, const float* __restrict__ bO,
    float* __restrict__ out, int nsp)
{
    __shared__ unsigned short Hs[64 * HS_STRIDE];     // 5120 B
    __shared__ unsigned short wOfL[8 * 512];          // 8192 B

    const int tid = threadIdx.x;
    const int qb  = blockIdx.x * 64;

    // build wO fragments in LDS (16 elements/thread)
    for (int idx = tid; idx < 8 * 512; idx += 256) {
        const int j  = idx & 7;
        const int ln = (idx >> 3) & 63;
        const int nt = idx >> 9;
        const int k = ((ln >> 4) << 3) + j;
        const int e = nt * 16 + (ln & 15);
        wOfL[idx] = (k < 24) ? f2bf(wO[k * 128 + e]) : (unsigned short)0;
    }

    {
        const int ql = tid >> 2;
        const int c8 = (tid & 3) * 8;     // dim chunk 0,8,16,24
        const int q  = qb + ql;
        float a[8] = {0.f, 0.f, 0.f, 0.f, 0.f, 0.f, 0.f, 0.f};
        if (c8 < 24) {                    // chunk 24..31 never written -> zeros
            for (int s = 0; s < nsp; ++s) {
                const __half2* p2 = (const __half2*)(Opart + ((size_t)s * N_ + q) * 32 + c8);
                #pragma unroll
                for (int j = 0; j < 4; ++j) {
                    const float2 f = __half22float2(p2[j]);
                    a[2 * j]     += f.x;
                    a[2 * j + 1] += f.y;
                }
            }
        }
        float ls = 0.f;
        for (int s = 0; s < nsp; ++s) ls += lpart[(size_t)s * N_ + q];
        const float inv = 1.0f / ls;
        uint4 pk;
        pk.x = pack2h(a[0] * inv, a[1] * inv);
        pk.y = pack2h(a[2] * inv, a[3] * inv);
        pk.z = pack2h(a[4] * inv, a[5] * inv);
        pk.w = pack2h(a[6] * inv, a[7] * inv);
        *(uint4*)(&Hs[ql * HS_STRIDE + c8]) = pk;
    }
    __syncthreads();

    const int lane = tid & 63;
    const int w    = tid >> 6;
    const int col  = lane & 15;
    const int quad = lane >> 4;
    const bfrag Hf = *(const bfrag*)(&Hs[(w * 16 + col) * HS_STRIDE + quad * 8]);
    #pragma unroll
    for (int nt = 0; nt < 8; ++nt) {
        const bfrag Wo = *(const bfrag*)(&wOfL[(nt * 64 + lane) * 8]);
        ffrag C = {0.f, 0.f, 0.f, 0.f};
        C = __builtin_amdgcn_mfma_f32_16x16x32_bf16(Hf, Wo, C, 0, 0, 0);
        const float bo = bO[nt * 16 + col];
        #pragma unroll
        for (int r = 0; r < 4; ++r)
            out[(size_t)(qb + w * 16 + quad * 4 + r) * 128 + nt * 16 + col] = C[r] + bo;
    }
}

extern "C" void kernel_launch(void* const* d_in, const int* in_sizes, int n_in,
                              void* d_out, int out_size, void* d_ws, size_t ws_size,
                              hipStream_t stream) {
    const float* x  = (const float*)d_in[0];
    const float* wQ = (const float*)d_in[1];
    const float* bQ = (const float*)d_in[2];
    const float* wK = (const float*)d_in[3];
    const float* bK = (const float*)d_in[4];
    const float* wV = (const float*)d_in[5];
    const float* bV = (const float*)d_in[6];
    const float* wO = (const float*)d_in[7];
    const float* bO = (const float*)d_in[8];
    float* out = (float*)d_out;

    unsigned short* ws16 = (unsigned short*)d_ws;
    unsigned short* Qbf = ws16;                                    // N*32 shorts
    unsigned short* Kbf = Qbf + (size_t)N_ * 32;                   // N*32
    unsigned short* Vt  = Kbf + (size_t)N_ * 32;                   // B*24*S
    __half* Opart = (__half*)(Vt + (size_t)B_ * 24 * S_);          // nsp*N*32 fp16
    const size_t baseBytes = (size_t)((char*)Opart - (char*)d_ws);

    int nsp = 4;
    while (nsp > 1) {
        const size_t need = baseBytes + (size_t)nsp * N_ * 32 * 2 + (size_t)nsp * N_ * 4;
        if (need <= ws_size) break;
        nsp >>= 1;
    }
    float* lpart = (float*)(Opart + (size_t)nsp * N_ * 32);

    proj_kernel<<<N_ / 64, 256, 0, stream>>>(x, wQ, bQ, wK, bK, wV, bV, Qbf, Kbf, Vt);
    attn_kernel<<<dim3(N_ / 128, nsp), 512, 0, stream>>>(Qbf, Kbf, Vt, Opart, lpart);
    combine_kernel<<<N_ / 64, 256, 0, stream>>>(Opart, lpart, wO, bO, out, nsp);
}